// Round 14
// baseline (467.557 us; speedup 1.0000x reference)
//
#include <hip/hip_runtime.h>
#include <hip/hip_bf16.h>
#include <cstddef>

#define HW 16384
#define WID 128

typedef __attribute__((ext_vector_type(8))) short short8;
typedef __attribute__((ext_vector_type(4))) float f32x4;

// async global->LDS, 4B per lane; LDS dest = wave-uniform base + lane*4
#define GLD4(g, l)                                                        \
    __builtin_amdgcn_global_load_lds(                                     \
        (const __attribute__((address_space(1))) unsigned int*)(g),       \
        (__attribute__((address_space(3))) unsigned int*)(l), 4, 0, 0)

__device__ __forceinline__ int wstart(int i) {
    // K=7, DIL=2, L=128: nh*d = 6
    if (i < 6) return i & 1;
    if (i >= 122) return 114 + (i & 1);
    return i - 6;
}
__device__ __forceinline__ int pbstart(int i) {
    if (i < 6) return 6 - (i >> 1);
    if (i >= 122) return (127 - i) >> 1;
    return 3;
}

// split f into hi/lo bf16 via HW RNE conversion (v_cvt_pk_bf16_f32)
__device__ __forceinline__ void bsplit(float f, unsigned short& h, unsigned short& l) {
    __hip_bfloat16 hb = __float2bfloat16(f);
    h = __builtin_bit_cast(unsigned short, hb);
    float hf = __bfloat162float(hb);
    l = __builtin_bit_cast(unsigned short, __float2bfloat16(f - hf));
}

// ---------------- split-bf16 MFMA GEMM with fused fp32 B-operand (r13) ----------------
template <bool QKV>
__global__ __launch_bounds__(256, 2) void gemm_mfma(
    const float* __restrict__ Wm, const float* __restrict__ Xf, size_t bstr,
    const float* __restrict__ bias, const float* __restrict__ sinp,
    const float* __restrict__ cosp, float* __restrict__ Y, int NMT, int MT) {
    __shared__ unsigned short As_h[128][40], As_l[128][40];
    __shared__ unsigned short Bs_h[128][40], Bs_l[128][40];
    const int bid = blockIdx.x;
    const int xcd = bid & 7, r = bid >> 3;
    const int mt = r % NMT;
    const int q2 = r / NMT;
    const int nt = xcd * 16 + (q2 & 15);
    const int b = q2 >> 4;
    const int t = threadIdx.x;
    const int lane = t & 63, wid = t >> 6;
    const int wm = wid >> 1, wn = wid & 1;
    const int m0 = mt * 128, n0 = nt * 128;

    f32x4 acc[4][4];
#pragma unroll
    for (int i = 0; i < 4; i++)
#pragma unroll
        for (int j = 0; j < 4; j++) acc[i][j] = (f32x4){0.f, 0.f, 0.f, 0.f};

    const int sr = t >> 1, sh = t & 1;
    const float* arow = Wm + (size_t)(m0 + sr) * 256 + sh * 16;
    const int pl = t & 127, khalf = (t >> 7) * 16;
    const float* xcol = Xf + (size_t)b * bstr + n0 + pl;

    for (int ks = 0; ks < 8; ks++) {
        {
            const float* ap = arow + ks * 32;
#pragma unroll
            for (int g = 0; g < 2; g++) {
                float4 f0 = *(const float4*)(ap + g * 8);
                float4 f1 = *(const float4*)(ap + g * 8 + 4);
                float ff[8] = {f0.x, f0.y, f0.z, f0.w, f1.x, f1.y, f1.z, f1.w};
                short8 vh, vl;
#pragma unroll
                for (int e = 0; e < 8; e++) {
                    unsigned short h, lo_;
                    bsplit(ff[e], h, lo_);
                    vh[e] = (short)h;
                    vl[e] = (short)lo_;
                }
                *(short8*)&As_h[sr][sh * 16 + g * 8] = vh;
                *(short8*)&As_l[sr][sh * 16 + g * 8] = vl;
            }
        }
        {
            const float* xc = xcol + (size_t)(ks * 32 + khalf) * HW;
            float vv[16];
#pragma unroll
            for (int e = 0; e < 16; e++) vv[e] = xc[(size_t)e * HW];
            short8 vh0, vh1, vl0, vl1;
#pragma unroll
            for (int e = 0; e < 8; e++) {
                unsigned short h, lo_;
                bsplit(vv[e], h, lo_);
                vh0[e] = (short)h;
                vl0[e] = (short)lo_;
                bsplit(vv[e + 8], h, lo_);
                vh1[e] = (short)h;
                vl1[e] = (short)lo_;
            }
            *(short8*)&Bs_h[pl][khalf] = vh0;
            *(short8*)&Bs_h[pl][khalf + 8] = vh1;
            *(short8*)&Bs_l[pl][khalf] = vl0;
            *(short8*)&Bs_l[pl][khalf + 8] = vl1;
        }
        __syncthreads();
        const int k8 = (lane >> 4) * 8;
        short8 a_h[4], a_l[4];
#pragma unroll
        for (int mi = 0; mi < 4; mi++) {
            int am = wm * 64 + mi * 16 + (lane & 15);
            a_h[mi] = *(const short8*)&As_h[am][k8];
            a_l[mi] = *(const short8*)&As_l[am][k8];
        }
#pragma unroll
        for (int ni = 0; ni < 4; ni++) {
            int bn = wn * 64 + ni * 16 + (lane & 15);
            short8 b_h = *(const short8*)&Bs_h[bn][k8];
            short8 b_l = *(const short8*)&Bs_l[bn][k8];
#pragma unroll
            for (int mi = 0; mi < 4; mi++) {
                acc[mi][ni] = __builtin_amdgcn_mfma_f32_16x16x32_bf16(a_h[mi], b_h, acc[mi][ni], 0, 0, 0);
                acc[mi][ni] = __builtin_amdgcn_mfma_f32_16x16x32_bf16(a_h[mi], b_l, acc[mi][ni], 0, 0, 0);
                acc[mi][ni] = __builtin_amdgcn_mfma_f32_16x16x32_bf16(a_l[mi], b_h, acc[mi][ni], 0, 0, 0);
            }
        }
        __syncthreads();
    }

    const int col = lane & 15, rq = (lane >> 4) * 4;
    const int s = QKV ? (mt >> 1) : 3;
#pragma unroll
    for (int mi = 0; mi < 4; mi++) {
        int mrow = m0 + wm * 64 + mi * 16 + rq;
        float b0 = bias[mrow], b1 = bias[mrow + 1], b2 = bias[mrow + 2], b3 = bias[mrow + 3];
#pragma unroll
        for (int ni = 0; ni < 4; ni++) {
            int p = n0 + wn * 64 + ni * 16 + col;
            float v0 = acc[mi][ni][0] + b0, v1 = acc[mi][ni][1] + b1;
            float v2 = acc[mi][ni][2] + b2, v3 = acc[mi][ni][3] + b3;
            if (QKV && s < 2) {
                int d0 = (mi & 1) * 16 + rq;
                const float* cp = cosp + (size_t)p * 32 + d0;
                const float* sp = sinp + (size_t)p * 32 + d0;
                float c0 = cp[0], c1 = cp[1], c2 = cp[2], c3 = cp[3];
                float s0 = sp[0], s1 = sp[1], s2 = sp[2], s3 = sp[3];
                float n0_ = v0 * c0 - v1 * s0, n1_ = v1 * c1 + v0 * s1;
                float n2_ = v2 * c2 - v3 * s2, n3_ = v3 * c3 + v2 * s3;
                if (s == 0) {
                    const float scl = 0.17677669529663687f;
                    n0_ *= scl; n1_ *= scl; n2_ *= scl; n3_ *= scl;
                }
                v0 = n0_; v1 = n1_; v2 = n2_; v3 = n3_;
            }
            float* yp = Y + ((size_t)b * MT + mrow) * HW + p;
            yp[0] = v0;
            yp[HW] = v1;
            yp[2 * HW] = v2;
            yp[3 * HW] = v3;
        }
    }
}

// ---------------- attention helpers: union rows shared by pixels i and i+2 ----------
// O = (wstart(i+2)-wstart(i))/2, wave-uniform (i uniform per wave).
template <int O>
__device__ __forceinline__ void qk2(const float* win, int aoff, float qA, float qB,
                                    float (&sl)[49], float (&sh)[49]) {
    const float* rw = win + aoff;
#pragma unroll
    for (int u = 0; u < 7 + O; u++) {
        float tp[7];
#pragma unroll
        for (int kj = 0; kj < 7; kj++) tp[kj] = rw[kj * 2];
        if (u < 7) {
#pragma unroll
            for (int kj = 0; kj < 7; kj++) sl[u * 7 + kj] = fmaf(qA, tp[kj], sl[u * 7 + kj]);
        }
        if (u >= O) {
#pragma unroll
            for (int kj = 0; kj < 7; kj++) sh[(u - O) * 7 + kj] = fmaf(qB, tp[kj], sh[(u - O) * 7 + kj]);
        }
        rw += 2 * WID;
    }
}

template <int O>
__device__ __forceinline__ void pv2(const float* win, int aoff, const float (&sl)[49],
                                    const float (&sh)[49], float& oA, float& oB) {
    const float* rw = win + aoff;
#pragma unroll
    for (int u = 0; u < 7 + O; u++) {
        float tp[7];
#pragma unroll
        for (int kj = 0; kj < 7; kj++) tp[kj] = rw[kj * 2];
        if (u < 7) {
#pragma unroll
            for (int kj = 0; kj < 7; kj++) oA = fmaf(sl[u * 7 + kj], tp[kj], oA);
        }
        if (u >= O) {
#pragma unroll
            for (int kj = 0; kj < 7; kj++) oB = fmaf(sh[(u - O) * 7 + kj], tp[kj], oB);
        }
        rw += 2 * WID;
    }
}

// ---------------- Neighborhood attention + fused LePE, v8 (vertical pair) ----------
// 256 thr = 2 ty-rows x 128 cols; thread computes pixels (i0+ty, j) and
// (i0+ty+2, j). Union tap rows serve both pixels (wave-uniform shift O).
// 16x128 window per channel, 2 ch/phase, 32 KB double-buffer, DMA + counted
// vmcnt. q via prefetched global register loads. Channel-plane fp32 stores
// (proven pattern). XCD-aware i-quad swizzle.
#define CWIN 2048  // 16*128
#define PB2 4096   // 2 channels
__global__ __launch_bounds__(256, 3) void attn_k(const float* __restrict__ qkv,
                                                 const float* __restrict__ rpb,
                                                 const float* __restrict__ wl,
                                                 const float* __restrict__ bl,
                                                 float* __restrict__ out) {
    __shared__ float sm[2 * PB2];
    const int t = threadIdx.x;
    const int ty = t >> 7;
    const int j = t & 127;
    const int bx = blockIdx.x;
    const int it = ((bx & 7) << 2) | (bx >> 3);  // XCD owns 4 consecutive i-quads
    const int n = blockIdx.y, b = blockIdx.z;
    const int i0 = it * 4;
    const int i = i0 + ty;  // pixel A; pixel B = i + 2
    const int r0 = wstart(i0);
    const int w64 = (t >> 6) * 64;

    const float* qb = qkv + ((size_t)b * 768 + n * 32) * HW;
    const float* kb = qb + (size_t)256 * HW;
    const float* vb = qb + (size_t)512 * HW;
    const int pA = i * WID + j;
    const int pB = pA + 2 * WID;

    // staging offsets (rows clamped at 127; clamped slots never read)
    int woff[8];
#pragma unroll
    for (int u = 0; u < 8; u++) {
        int row = r0 + 2 * u + ty;
        if (row > 127) row = 127;
        woff[u] = row * WID + j;
    }

    const int hs = wstart(i), ws_ = wstart(j);
    const int O1 = (wstart(i + 2) - hs) >> 1;  // wave-uniform 0/1
    const int aoff = (hs - r0) * WID + ws_;

    float sl[49], sh[49];
    {
        const float* rp = rpb + n * 169;
        const int phA = pbstart(i), phB = pbstart(i + 2), pw = pbstart(j);
#pragma unroll
        for (int ki = 0; ki < 7; ki++)
#pragma unroll
            for (int kj = 0; kj < 7; kj++) {
                sl[ki * 7 + kj] = rp[(phA + ki) * 13 + (pw + kj)];
                sh[ki * 7 + kj] = rp[(phB + ki) * 13 + (pw + kj)];
            }
    }

    // ---- prologue: stage ch0,1 k windows; load ch0,1 q ----
#pragma unroll
    for (int s = 0; s < 2; s++) {
        const float* kp = kb + (size_t)s * HW;
#pragma unroll
        for (int u = 0; u < 8; u++) GLD4(kp + woff[u], &sm[s * CWIN + u * 256 + w64]);
    }
    float qA0 = qb[pA], qB0 = qb[pB];
    float qA1 = qb[HW + pA], qB1 = qb[HW + pB];

    // ---- QK^T: 16 two-channel phases ----
    for (int cp = 0; cp < 16; cp++) {
        const float* bc = sm + (cp & 1) * PB2;
        float* bnx = sm + ((cp + 1) & 1) * PB2;
        float qnA0 = 0.f, qnB0 = 0.f, qnA1 = 0.f, qnB1 = 0.f;
        if (cp < 15) {
#pragma unroll
            for (int s = 0; s < 2; s++) {
                const float* kp = kb + (size_t)(2 * (cp + 1) + s) * HW;
#pragma unroll
                for (int u = 0; u < 8; u++) GLD4(kp + woff[u], &bnx[s * CWIN + u * 256 + w64]);
            }
            qnA0 = qb[(size_t)(2 * cp + 2) * HW + pA];
            qnB0 = qb[(size_t)(2 * cp + 2) * HW + pB];
            qnA1 = qb[(size_t)(2 * cp + 3) * HW + pA];
            qnB1 = qb[(size_t)(2 * cp + 3) * HW + pB];
            asm volatile("s_waitcnt vmcnt(20)" ::: "memory");
        } else {
#pragma unroll
            for (int s = 0; s < 2; s++) {
                const float* vp = vb + (size_t)s * HW;
#pragma unroll
                for (int u = 0; u < 8; u++) GLD4(vp + woff[u], &bnx[s * CWIN + u * 256 + w64]);
            }
            asm volatile("s_waitcnt vmcnt(16)" ::: "memory");
        }
        __builtin_amdgcn_s_barrier();
        __builtin_amdgcn_s_setprio(1);
        if (O1) {
            qk2<1>(bc, aoff, qA0, qB0, sl, sh);
            qk2<1>(bc + CWIN, aoff, qA1, qB1, sl, sh);
        } else {
            qk2<0>(bc, aoff, qA0, qB0, sl, sh);
            qk2<0>(bc + CWIN, aoff, qA1, qB1, sl, sh);
        }
        __builtin_amdgcn_s_setprio(0);
        qA0 = qnA0; qB0 = qnB0; qA1 = qnA1; qB1 = qnB1;
        __builtin_amdgcn_s_barrier();
    }

    // ---- softmax over 49, both pixels (v ch0,1 in flight) ----
    float mx0 = sl[0], mx1 = sh[0];
#pragma unroll
    for (int u = 1; u < 49; u++) {
        mx0 = fmaxf(mx0, sl[u]);
        mx1 = fmaxf(mx1, sh[u]);
    }
    float s0 = 0.f, s1 = 0.f;
#pragma unroll
    for (int u = 0; u < 49; u++) {
        sl[u] = __expf(sl[u] - mx0); s0 += sl[u];
        sh[u] = __expf(sh[u] - mx1); s1 += sh[u];
    }
    float inv0 = 1.f / s0, inv1 = 1.f / s1;
#pragma unroll
    for (int u = 0; u < 49; u++) {
        sl[u] *= inv0;
        sh[u] *= inv1;
    }

    // ---- PV + LePE: 16 two-channel phases ----
    float* ob = out + ((size_t)b * 768 + n * 32) * HW;
    const float* wlb = wl + (size_t)(n * 32) * 25;
    const float* blb = bl + n * 32;
    for (int cp = 0; cp < 16; cp++) {
        const float* bc = sm + (cp & 1) * PB2;
        float* bnx = sm + ((cp + 1) & 1) * PB2;
        if (cp < 15) {
#pragma unroll
            for (int s = 0; s < 2; s++) {
                const float* vp = vb + (size_t)(2 * (cp + 1) + s) * HW;
#pragma unroll
                for (int u = 0; u < 8; u++) GLD4(vp + woff[u], &bnx[s * CWIN + u * 256 + w64]);
            }
            asm volatile("s_waitcnt vmcnt(16)" ::: "memory");
        } else {
            asm volatile("s_waitcnt vmcnt(0)" ::: "memory");
        }
        __builtin_amdgcn_s_barrier();
        __builtin_amdgcn_s_setprio(1);
#pragma unroll
        for (int s = 0; s < 2; s++) {
            const int ch = 2 * cp + s;
            const float* win = bc + s * CWIN;
            float oA = 0.f, oB = 0.f;
            if (O1) pv2<1>(win, aoff, sl, sh, oA, oB);
            else    pv2<0>(win, aoff, sl, sh, oA, oB);
            // LePE 5x5 for both pixels from shared 7-row strip
            const float* wrow = wlb + ch * 25;
            float lA = blb[ch], lB = lA;
            const float* wb2 = win + (i - 2 - r0) * WID + (j - 2);
#pragma unroll
            for (int dd = 0; dd < 7; dd++) {
                int ii = i - 2 + dd;
                if ((unsigned)ii < 128u) {
                    const float* srow = wb2 + dd * WID;
#pragma unroll
                    for (int dj = 0; dj < 5; dj++) {
                        int jj = j - 2 + dj;
                        if ((unsigned)jj < 128u) {
                            float tv = srow[dj];
                            if (dd <= 4) lA = fmaf(wrow[dd * 5 + dj], tv, lA);
                            if (dd >= 2) lB = fmaf(wrow[(dd - 2) * 5 + dj], tv, lB);
                        }
                    }
                }
            }
            float* op = ob + (size_t)ch * HW;
            op[pA] = oA + lA;
            op[pB] = oB + lB;
        }
        __builtin_amdgcn_s_setprio(0);
        __builtin_amdgcn_s_barrier();
    }
}

extern "C" void kernel_launch(void* const* d_in, const int* in_sizes, int n_in,
                              void* d_out, int out_size, void* d_ws, size_t ws_size,
                              hipStream_t stream) {
    const float* x = (const float*)d_in[0];
    const float* sinp = (const float*)d_in[1];
    const float* cosp = (const float*)d_in[2];
    const float* w_qkv = (const float*)d_in[3];
    const float* b_qkv = (const float*)d_in[4];
    const float* w_lepe = (const float*)d_in[5];
    const float* b_lepe = (const float*)d_in[6];
    const float* w_proj = (const float*)d_in[7];
    const float* b_proj = (const float*)d_in[8];
    const float* rpb = (const float*)d_in[9];
    float* out = (float*)d_out;

    // ws: qkvb fp32 [b][768][HW]; q-region doubles as attn+lepe output.
    float* qkvb = (float*)d_ws;

    // 1) QKV projection (MFMA, fused fp32-B split) + fused bias/RoPE/scale
    gemm_mfma<true><<<dim3(3072), 256, 0, stream>>>(w_qkv, x, (size_t)256 * HW, b_qkv,
                                                    sinp, cosp, qkvb, 6, 768);
    // 2) neighborhood attention + fused LePE -> q-region of qkvb
    attn_k<<<dim3(32, 8, 4), 256, 0, stream>>>(qkvb, rpb, w_lepe, b_lepe, qkvb);
    // 3) output projection (MFMA, fused fp32-B split from q-region) -> d_out
    gemm_mfma<false><<<dim3(1024), 256, 0, stream>>>(w_proj, qkvb, (size_t)768 * HW, b_proj,
                                                     nullptr, nullptr, out, 2, 256);
}

// Round 15
// 363.864 us; speedup vs baseline: 1.2850x; 1.2850x over previous
//
#include <hip/hip_runtime.h>
#include <hip/hip_bf16.h>
#include <cstddef>

#define HW 16384
#define WID 128

typedef __attribute__((ext_vector_type(8))) short short8;
typedef __attribute__((ext_vector_type(4))) float f32x4;

// async global->LDS, 4B per lane; LDS dest = wave-uniform base + lane*4
#define GLD4(g, l)                                                        \
    __builtin_amdgcn_global_load_lds(                                     \
        (const __attribute__((address_space(1))) unsigned int*)(g),       \
        (__attribute__((address_space(3))) unsigned int*)(l), 4, 0, 0)

__device__ __forceinline__ int wstart(int i) {
    // K=7, DIL=2, L=128: nh*d = 6
    if (i < 6) return i & 1;
    if (i >= 122) return 114 + (i & 1);
    return i - 6;
}
__device__ __forceinline__ int pbstart(int i) {
    if (i < 6) return 6 - (i >> 1);
    if (i >= 122) return (127 - i) >> 1;
    return 3;
}

// split f into hi/lo bf16 via HW RNE conversion (v_cvt_pk_bf16_f32 path)
__device__ __forceinline__ void bsplit(float f, unsigned short& h, unsigned short& l) {
    __hip_bfloat16 hb = __float2bfloat16(f);
    h = __builtin_bit_cast(unsigned short, hb);
    float hf = __bfloat162float(hb);
    l = __builtin_bit_cast(unsigned short, __float2bfloat16(f - hf));
}

// ---------------- split-bf16 MFMA GEMM with fused fp32 B-operand ----------------
// r13 structure + register double-buffer: K-step ks+1's A/B global loads are
// issued before ks's MFMA section, hiding load latency under the 48 MFMAs.
template <bool QKV>
__global__ __launch_bounds__(256, 2) void gemm_mfma(
    const float* __restrict__ Wm, const float* __restrict__ Xf, size_t bstr,
    const float* __restrict__ bias, const float* __restrict__ sinp,
    const float* __restrict__ cosp, float* __restrict__ Y, int NMT, int MT) {
    __shared__ unsigned short As_h[128][40], As_l[128][40];
    __shared__ unsigned short Bs_h[128][40], Bs_l[128][40];
    const int bid = blockIdx.x;
    const int xcd = bid & 7, r = bid >> 3;
    const int mt = r % NMT;
    const int q2 = r / NMT;
    const int nt = xcd * 16 + (q2 & 15);
    const int b = q2 >> 4;
    const int t = threadIdx.x;
    const int lane = t & 63, wid = t >> 6;
    const int wm = wid >> 1, wn = wid & 1;
    const int m0 = mt * 128, n0 = nt * 128;

    f32x4 acc[4][4];
#pragma unroll
    for (int i = 0; i < 4; i++)
#pragma unroll
        for (int j = 0; j < 4; j++) acc[i][j] = (f32x4){0.f, 0.f, 0.f, 0.f};

    const int sr = t >> 1, sh = t & 1;
    const float* arow = Wm + (size_t)(m0 + sr) * 256 + sh * 16;
    const int pl = t & 127, khalf = (t >> 7) * 16;
    const float* xcol = Xf + (size_t)b * bstr + n0 + pl;

    // ---- preload K-step 0 into registers ----
    float av[16], vv[16];
    {
        const float* ap = arow;
#pragma unroll
        for (int g = 0; g < 4; g++) {
            float4 f0 = *(const float4*)(ap + g * 4);
            av[g * 4 + 0] = f0.x; av[g * 4 + 1] = f0.y;
            av[g * 4 + 2] = f0.z; av[g * 4 + 3] = f0.w;
        }
        const float* xc = xcol + (size_t)khalf * HW;
#pragma unroll
        for (int e = 0; e < 16; e++) vv[e] = xc[(size_t)e * HW];
    }

    for (int ks = 0; ks < 8; ks++) {
        // cvt + LDS store from registers
        {
            short8 vh0, vh1, vl0, vl1;
#pragma unroll
            for (int e = 0; e < 8; e++) {
                unsigned short h, lo_;
                bsplit(av[e], h, lo_);
                vh0[e] = (short)h; vl0[e] = (short)lo_;
                bsplit(av[e + 8], h, lo_);
                vh1[e] = (short)h; vl1[e] = (short)lo_;
            }
            *(short8*)&As_h[sr][sh * 16] = vh0;
            *(short8*)&As_h[sr][sh * 16 + 8] = vh1;
            *(short8*)&As_l[sr][sh * 16] = vl0;
            *(short8*)&As_l[sr][sh * 16 + 8] = vl1;
#pragma unroll
            for (int e = 0; e < 8; e++) {
                unsigned short h, lo_;
                bsplit(vv[e], h, lo_);
                vh0[e] = (short)h; vl0[e] = (short)lo_;
                bsplit(vv[e + 8], h, lo_);
                vh1[e] = (short)h; vl1[e] = (short)lo_;
            }
            *(short8*)&Bs_h[pl][khalf] = vh0;
            *(short8*)&Bs_h[pl][khalf + 8] = vh1;
            *(short8*)&Bs_l[pl][khalf] = vl0;
            *(short8*)&Bs_l[pl][khalf + 8] = vl1;
        }
        // prefetch K-step ks+1 (latency hides under the MFMA section below)
        if (ks < 7) {
            const float* ap = arow + (ks + 1) * 32;
#pragma unroll
            for (int g = 0; g < 4; g++) {
                float4 f0 = *(const float4*)(ap + g * 4);
                av[g * 4 + 0] = f0.x; av[g * 4 + 1] = f0.y;
                av[g * 4 + 2] = f0.z; av[g * 4 + 3] = f0.w;
            }
            const float* xc = xcol + (size_t)((ks + 1) * 32 + khalf) * HW;
#pragma unroll
            for (int e = 0; e < 16; e++) vv[e] = xc[(size_t)e * HW];
        }
        __syncthreads();
        const int k8 = (lane >> 4) * 8;
        short8 a_h[4], a_l[4];
#pragma unroll
        for (int mi = 0; mi < 4; mi++) {
            int am = wm * 64 + mi * 16 + (lane & 15);
            a_h[mi] = *(const short8*)&As_h[am][k8];
            a_l[mi] = *(const short8*)&As_l[am][k8];
        }
#pragma unroll
        for (int ni = 0; ni < 4; ni++) {
            int bn = wn * 64 + ni * 16 + (lane & 15);
            short8 b_h = *(const short8*)&Bs_h[bn][k8];
            short8 b_l = *(const short8*)&Bs_l[bn][k8];
#pragma unroll
            for (int mi = 0; mi < 4; mi++) {
                acc[mi][ni] = __builtin_amdgcn_mfma_f32_16x16x32_bf16(a_h[mi], b_h, acc[mi][ni], 0, 0, 0);
                acc[mi][ni] = __builtin_amdgcn_mfma_f32_16x16x32_bf16(a_h[mi], b_l, acc[mi][ni], 0, 0, 0);
                acc[mi][ni] = __builtin_amdgcn_mfma_f32_16x16x32_bf16(a_l[mi], b_h, acc[mi][ni], 0, 0, 0);
            }
        }
        __syncthreads();
    }

    const int col = lane & 15, rq = (lane >> 4) * 4;
    const int s = QKV ? (mt >> 1) : 3;
#pragma unroll
    for (int mi = 0; mi < 4; mi++) {
        int mrow = m0 + wm * 64 + mi * 16 + rq;
        float b0 = bias[mrow], b1 = bias[mrow + 1], b2 = bias[mrow + 2], b3 = bias[mrow + 3];
#pragma unroll
        for (int ni = 0; ni < 4; ni++) {
            int p = n0 + wn * 64 + ni * 16 + col;
            float v0 = acc[mi][ni][0] + b0, v1 = acc[mi][ni][1] + b1;
            float v2 = acc[mi][ni][2] + b2, v3 = acc[mi][ni][3] + b3;
            if (QKV && s < 2) {
                int d0 = (mi & 1) * 16 + rq;
                const float* cp = cosp + (size_t)p * 32 + d0;
                const float* sp = sinp + (size_t)p * 32 + d0;
                float c0 = cp[0], c1 = cp[1], c2 = cp[2], c3 = cp[3];
                float s0 = sp[0], s1 = sp[1], s2 = sp[2], s3 = sp[3];
                float n0_ = v0 * c0 - v1 * s0, n1_ = v1 * c1 + v0 * s1;
                float n2_ = v2 * c2 - v3 * s2, n3_ = v3 * c3 + v2 * s3;
                if (s == 0) {
                    const float scl = 0.17677669529663687f;
                    n0_ *= scl; n1_ *= scl; n2_ *= scl; n3_ *= scl;
                }
                v0 = n0_; v1 = n1_; v2 = n2_; v3 = n3_;
            }
            float* yp = Y + ((size_t)b * MT + mrow) * HW + p;
            yp[0] = v0;
            yp[HW] = v1;
            yp[2 * HW] = v2;
            yp[3 * HW] = v3;
        }
    }
}

// ---------------- Neighborhood attention + fused LePE (r13, proven 223 µs) ----------
#define CW 2048    // per-channel slot: 14x128 window (1792) + q 2x128 (256)
#define PBUF 4096  // 2 channels per phase buffer
__global__ __launch_bounds__(256) void attn_k(const float* __restrict__ qkv,
                                              const float* __restrict__ rpb,
                                              const float* __restrict__ wl,
                                              const float* __restrict__ bl,
                                              float* __restrict__ out) {
    __shared__ float sm[2 * PBUF];
    const int t = threadIdx.x;
    const int ty = t >> 7;
    const int j = t & 127;
    const int bx = blockIdx.x;
    const int ip = ((bx & 7) << 3) | (bx >> 3);  // XCD bx&7 owns 8 consecutive i-pairs
    const int i0 = ip * 2;
    const int i = i0 + ty;
    const int n = blockIdx.y, b = blockIdx.z;
    const int r0 = wstart(i0);      // window rows r0..r0+13 (always <= 127)
    const int w64 = (t >> 6) * 64;  // wave-uniform LDS lane base

    const float* qb = qkv + ((size_t)b * 768 + n * 32) * HW;
    const float* kb = qb + (size_t)256 * HW;
    const float* vb = qb + (size_t)512 * HW;
    const int p = i * WID + j;
    const float* qrow = qb + i0 * WID;  // + c*HW + t
    const float* krow = kb + r0 * WID;
    const float* vrow = vb + r0 * WID;

    const int hs = wstart(i), ws_ = wstart(j);
    const int ph = pbstart(i), pw = pbstart(j);

    float sc[49];
    const float* rp = rpb + n * 169;
#pragma unroll
    for (int ki = 0; ki < 7; ki++)
#pragma unroll
        for (int kj = 0; kj < 7; kj++)
            sc[ki * 7 + kj] = rp[(ph + ki) * 13 + (pw + kj)];

    const int aoff = (hs - r0) * WID + ws_;  // attn tap base within a window

    // ---- prologue: stage channels 0,1 (k windows + q rows) into buf0 ----
#pragma unroll
    for (int s = 0; s < 2; s++) {
        const float* kp = krow + (size_t)s * HW;
#pragma unroll
        for (int u = 0; u < 7; u++) GLD4(kp + u * 256 + t, &sm[s * CW + u * 256 + w64]);
        GLD4(qrow + (size_t)s * HW + t, &sm[s * CW + 1792 + w64]);
    }

    // ---- QK^T: 16 two-channel phases ----
    for (int cp = 0; cp < 16; cp++) {
        float* bc = sm + (cp & 1) * PBUF;
        float* bnx = sm + ((cp + 1) & 1) * PBUF;
        if (cp < 15) {
#pragma unroll
            for (int s = 0; s < 2; s++) {
                const int c = 2 * (cp + 1) + s;
                const float* kp = krow + (size_t)c * HW;
#pragma unroll
                for (int u = 0; u < 7; u++) GLD4(kp + u * 256 + t, &bnx[s * CW + u * 256 + w64]);
                GLD4(qrow + (size_t)c * HW + t, &bnx[s * CW + 1792 + w64]);
            }
            asm volatile("s_waitcnt vmcnt(16)" ::: "memory");
        } else {
            // stage v channels 0,1 (no q) so they fly during softmax
#pragma unroll
            for (int s = 0; s < 2; s++) {
                const float* vp = vrow + (size_t)s * HW;
#pragma unroll
                for (int u = 0; u < 7; u++) GLD4(vp + u * 256 + t, &bnx[s * CW + u * 256 + w64]);
            }
            asm volatile("s_waitcnt vmcnt(14)" ::: "memory");
        }
        __builtin_amdgcn_s_barrier();
        __builtin_amdgcn_s_setprio(1);
#pragma unroll
        for (int s = 0; s < 2; s++) {
            const float* bs = bc + s * CW;
            float qc = bs[1792 + t];
            const float* smb = bs + aoff;
#pragma unroll
            for (int ki = 0; ki < 7; ki++) {
                const float* kib = smb + ki * 256;
#pragma unroll
                for (int kj = 0; kj < 7; kj++)
                    sc[ki * 7 + kj] = fmaf(qc, kib[kj * 2], sc[ki * 7 + kj]);
            }
        }
        __builtin_amdgcn_s_setprio(0);
        __builtin_amdgcn_s_barrier();
    }

    // ---- softmax over 49 (v channels 0,1 in flight) ----
    float mx = sc[0];
#pragma unroll
    for (int u = 1; u < 49; u++) mx = fmaxf(mx, sc[u]);
    float sum = 0.0f;
#pragma unroll
    for (int u = 0; u < 49; u++) {
        sc[u] = __expf(sc[u] - mx);
        sum += sc[u];
    }
    float inv = 1.0f / sum;
#pragma unroll
    for (int u = 0; u < 49; u++) sc[u] *= inv;

    // ---- PV + LePE: 16 two-channel phases ----
    float* ob = out + ((size_t)b * 768 + n * 32) * HW + p;
    const float* wbase = wl + (size_t)(n * 32) * 25;
    const float* blb = bl + n * 32;
    for (int cp = 0; cp < 16; cp++) {
        float* bc = sm + (cp & 1) * PBUF;
        float* bnx = sm + ((cp + 1) & 1) * PBUF;
        if (cp < 15) {
#pragma unroll
            for (int s = 0; s < 2; s++) {
                const int c = 2 * (cp + 1) + s;
                const float* vp = vrow + (size_t)c * HW;
#pragma unroll
                for (int u = 0; u < 7; u++) GLD4(vp + u * 256 + t, &bnx[s * CW + u * 256 + w64]);
            }
            asm volatile("s_waitcnt vmcnt(14)" ::: "memory");
        } else {
            asm volatile("s_waitcnt vmcnt(0)" ::: "memory");
        }
        __builtin_amdgcn_s_barrier();
        __builtin_amdgcn_s_setprio(1);
#pragma unroll
        for (int s = 0; s < 2; s++) {
            const int ch = 2 * cp + s;
            const float* bs = bc + s * CW;
            const float* smb = bs + aoff;
            float oc = 0.0f;
#pragma unroll
            for (int ki = 0; ki < 7; ki++) {
                const float* kib = smb + ki * 256;
#pragma unroll
                for (int kj = 0; kj < 7; kj++)
                    oc = fmaf(sc[ki * 7 + kj], kib[kj * 2], oc);
            }
            // LePE 5x5 depthwise from the same staged window
            const float* wrow = wbase + ch * 25;
            float lac = blb[ch];
#pragma unroll
            for (int di = 0; di < 5; di++) {
                int ii = i + di - 2;
                if ((unsigned)ii < 128u) {
                    const float* srow = bs + (ii - r0) * WID;
                    const float* wr = wrow + di * 5;
#pragma unroll
                    for (int dj = 0; dj < 5; dj++) {
                        int jj = j + dj - 2;
                        if ((unsigned)jj < 128u)
                            lac = fmaf(wr[dj], srow[jj], lac);
                    }
                }
            }
            ob[(size_t)ch * HW] = oc + lac;
        }
        __builtin_amdgcn_s_setprio(0);
        __builtin_amdgcn_s_barrier();
    }
}

extern "C" void kernel_launch(void* const* d_in, const int* in_sizes, int n_in,
                              void* d_out, int out_size, void* d_ws, size_t ws_size,
                              hipStream_t stream) {
    const float* x = (const float*)d_in[0];
    const float* sinp = (const float*)d_in[1];
    const float* cosp = (const float*)d_in[2];
    const float* w_qkv = (const float*)d_in[3];
    const float* b_qkv = (const float*)d_in[4];
    const float* w_lepe = (const float*)d_in[5];
    const float* b_lepe = (const float*)d_in[6];
    const float* w_proj = (const float*)d_in[7];
    const float* b_proj = (const float*)d_in[8];
    const float* rpb = (const float*)d_in[9];
    float* out = (float*)d_out;

    // ws layout: qkvb fp32 [b][768][HW] (201 MB); q-region doubles as
    // attn+lepe output, read directly by the proj GEMM (B-fusion, no pack).
    float* qkvb = (float*)d_ws;

    // 1) QKV projection (MFMA, fused fp32-B split) + fused bias/RoPE/scale -> qkvb
    gemm_mfma<true><<<dim3(3072), 256, 0, stream>>>(w_qkv, x, (size_t)256 * HW, b_qkv,
                                                    sinp, cosp, qkvb, 6, 768);
    // 2) neighborhood attention + fused LePE -> q-region of qkvb
    attn_k<<<dim3(64, 8, 4), 256, 0, stream>>>(qkvb, rpb, w_lepe, b_lepe, qkvb);
    // 3) output projection (MFMA, fused fp32-B split from q-region) -> d_out
    gemm_mfma<false><<<dim3(1024), 256, 0, stream>>>(w_proj, qkvb, (size_t)768 * HW, b_proj,
                                                     nullptr, nullptr, out, 2, 256);
}